// Round 1
// 2728.415 us; speedup vs baseline: 2.8384x; 2.8384x over previous
//
#include <hip/hip_runtime.h>

// ---------------------------------------------------------------------------
// Round 5: register-tiled fp32 vector GEMM restructure.
//   Kernel 1 (attn4): block = (window, 4-head group). Phase 1 builds the
//   49x256 kv tile with a 13x4 fp32 register tile per thread (double-buffered
//   input chunks in LDS, float4 weight streaming). Phases 2-4 per head:
//   q-slice staged to LDS, vectorized QK^T, row softmax, vectorized PV.
//   Kernel 2 (proj32): 32x512 tile, 16x4 register tile per thread, in-place.
// All math fp32 (matches reference tolerance envelope of the green anchor).
// ---------------------------------------------------------------------------

#define FMA4(accv, f, w0, w1, w2, w3)                                          \
  accv.x = fmaf(f.x, w0.x, accv.x); accv.x = fmaf(f.y, w1.x, accv.x);          \
  accv.x = fmaf(f.z, w2.x, accv.x); accv.x = fmaf(f.w, w3.x, accv.x);          \
  accv.y = fmaf(f.x, w0.y, accv.y); accv.y = fmaf(f.y, w1.y, accv.y);          \
  accv.y = fmaf(f.z, w2.y, accv.y); accv.y = fmaf(f.w, w3.y, accv.y);          \
  accv.z = fmaf(f.x, w0.z, accv.z); accv.z = fmaf(f.y, w1.z, accv.z);          \
  accv.z = fmaf(f.z, w2.z, accv.z); accv.z = fmaf(f.w, w3.z, accv.z);          \
  accv.w = fmaf(f.x, w0.w, accv.w); accv.w = fmaf(f.y, w1.w, accv.w);          \
  accv.w = fmaf(f.z, w2.w, accv.w); accv.w = fmaf(f.w, w3.w, accv.w);

// kv_s stride 260 floats = 65 float4 (odd) -> conflict-free lane-varying b128.
__global__ __launch_bounds__(256) void attn4(
    const float* __restrict__ inp, const float* __restrict__ qg,
    const float* __restrict__ W, const float* __restrict__ b,
    const float* __restrict__ bt, float* __restrict__ out) {
    __shared__ float kv_s[49][260];     // 50960 B: c<128 -> k, c>=128 -> v
    __shared__ float S_s[49][53];       // 10388 B (odd stride: softmax reads)
    __shared__ float inp_s[2][49][32];  // 12544 B: dbuf input chunks / q slice

    const int win = blockIdx.x;   // 0..1023
    const int hg  = blockIdx.y;   // head group 0..3 (heads hg*4 .. hg*4+3)
    const int t   = threadIdx.x;  // 0..255
    const int c4  = t & 63;       // float4 column 0..63 (256 cols)
    const int rg  = t >> 6;       // row group 0..3 (rows rg, rg+4, ...)

    // global W column base: c4<32 -> k cols, c4>=32 -> v cols
    const int colbase = (c4 < 32) ? (hg * 128 + (c4 << 2))
                                  : (512 + hg * 128 + ((c4 - 32) << 2));
    const float* ip = inp + (size_t)win * 49 * 512;

    // ---- phase 1: kv tile = inp[win] @ W[:, cols] + b --------------------
    float4 acc[13];
#pragma unroll
    for (int rr = 0; rr < 13; ++rr) acc[rr] = make_float4(0.f, 0.f, 0.f, 0.f);
    const float4 bias = *(const float4*)(b + colbase);

    // prologue: stage chunk 0 into buffer 0
    for (int o = t; o < 392; o += 256) {
        int r = o >> 3, kk = (o & 7) << 2;
        *(float4*)&inp_s[0][r][kk] = *(const float4*)(ip + (size_t)r * 512 + kk);
    }
    __syncthreads();

    for (int kc = 0; kc < 512; kc += 32) {
        const int cur = (kc >> 5) & 1;
        // stage next chunk into the other buffer (overlaps with compute)
        if (kc + 32 < 512) {
            for (int o = t; o < 392; o += 256) {
                int r = o >> 3, kk = (o & 7) << 2;
                *(float4*)&inp_s[cur ^ 1][r][kk] =
                    *(const float4*)(ip + (size_t)r * 512 + kc + 32 + kk);
            }
        }
        const float* Wp = W + ((size_t)kc << 10) + colbase;
#pragma unroll
        for (int k4 = 0; k4 < 8; ++k4) {
            const float* wr = Wp + ((size_t)(k4 << 2) << 10);
            float4 w0 = *(const float4*)(wr);
            float4 w1 = *(const float4*)(wr + 1024);
            float4 w2 = *(const float4*)(wr + 2048);
            float4 w3 = *(const float4*)(wr + 3072);
#pragma unroll
            for (int rr = 0; rr < 13; ++rr) {
                const int r = rg + (rr << 2);
                if (r < 49) {
                    float4 f = *(const float4*)&inp_s[cur][r][k4 << 2];
                    FMA4(acc[rr], f, w0, w1, w2, w3)
                }
            }
        }
        __syncthreads();
    }
    // writeback kv tile (+bias)
#pragma unroll
    for (int rr = 0; rr < 13; ++rr) {
        const int r = rg + (rr << 2);
        if (r < 49) {
            float4 res = make_float4(acc[rr].x + bias.x, acc[rr].y + bias.y,
                                     acc[rr].z + bias.z, acc[rr].w + bias.w);
            *(float4*)&kv_s[r][c4 << 2] = res;
        }
    }
    __syncthreads();

    // ---- phases 2-4 per head --------------------------------------------
    const float* qwin = qg + (size_t)(win >> 4) * 49 * 512 + hg * 128;
    for (int hh = 0; hh < 4; ++hh) {
        const int H = (hg << 2) + hh;
        // stage q head slice (49x32) into inp_s[0]
        for (int o = t; o < 392; o += 256) {
            int r = o >> 3, dd = (o & 7) << 2;
            *(float4*)&inp_s[0][r][dd] =
                *(const float4*)(qwin + (size_t)r * 512 + (hh << 5) + dd);
        }
        __syncthreads();

        // S[i][j] = scale * q_i . k_j + bias(rel(i,j))
        for (int o = t; o < 2401; o += 256) {
            int i = o / 49, j = o - i * 49;
            float a = 0.f;
#pragma unroll
            for (int d4 = 0; d4 < 8; ++d4) {
                float4 qv = *(const float4*)&inp_s[0][i][d4 << 2];
                float4 kf = *(const float4*)&kv_s[j][(hh << 5) + (d4 << 2)];
                a = fmaf(qv.x, kf.x, a); a = fmaf(qv.y, kf.y, a);
                a = fmaf(qv.z, kf.z, a); a = fmaf(qv.w, kf.w, a);
            }
            int ih = i / 7, iw = i - ih * 7;
            int jh = j / 7, jw = j - jh * 7;
            int idx = (ih - jh + 6) * 13 + (iw - jw + 6);
            S_s[i][j] = a * 0.17677669529663687f + bt[idx * 16 + H];
        }
        __syncthreads();

        // softmax per row
        if (t < 49) {
            float mx = -1e30f;
#pragma unroll 7
            for (int j = 0; j < 49; ++j) mx = fmaxf(mx, S_s[t][j]);
            float sum = 0.f;
#pragma unroll 7
            for (int j = 0; j < 49; ++j) {
                float e = __expf(S_s[t][j] - mx);
                S_s[t][j] = e; sum += e;
            }
            float inv = 1.f / sum;
#pragma unroll 7
            for (int j = 0; j < 49; ++j) S_s[t][j] *= inv;
        }
        __syncthreads();

        // X[i][d] = sum_j P[i][j] * v[j][d]
        for (int o = t; o < 392; o += 256) {
            int i = o >> 3, dd = (o & 7) << 2;
            float4 a4 = make_float4(0.f, 0.f, 0.f, 0.f);
#pragma unroll 7
            for (int j = 0; j < 49; ++j) {
                float p = S_s[i][j];
                float4 vf = *(const float4*)&kv_s[j][128 + (hh << 5) + dd];
                a4.x = fmaf(p, vf.x, a4.x); a4.y = fmaf(p, vf.y, a4.y);
                a4.z = fmaf(p, vf.z, a4.z); a4.w = fmaf(p, vf.w, a4.w);
            }
            *(float4*)(out + ((size_t)win * 49 + i) * 512 + (H << 5) + dd) = a4;
        }
        __syncthreads();
    }
}

// Kernel 2: in-place out = out @ proj_w + proj_b. 32 rows/block, each thread
// owns a 16-row x 4-col fp32 accumulator tile. Race-free (own rows only).
__global__ __launch_bounds__(256) void proj32(
    const float* __restrict__ pw, const float* __restrict__ pb,
    float* __restrict__ io) {
    __shared__ float X_s[32][516];  // 66048 B, float4-aligned rows
    const int m0 = blockIdx.x << 5;
    const int t  = threadIdx.x;
    const int c4 = (t & 127) << 2;  // cols c4..c4+3
    const int rg = t >> 7;          // 0..1 -> rows rg*16 .. rg*16+15

    // stage 32x512 rows
    for (int o = t; o < 4096; o += 256) {
        int r = o >> 7, cc = (o & 127) << 2;
        *(float4*)&X_s[r][cc] =
            *(const float4*)(io + ((size_t)(m0 + r)) * 512 + cc);
    }
    __syncthreads();

    const float4 bias = *(const float4*)(pb + c4);
    float4 acc[16];
#pragma unroll
    for (int r = 0; r < 16; ++r) acc[r] = bias;

    const float* wp = pw + c4;
    for (int k4 = 0; k4 < 128; ++k4) {
        const float* wr = wp + ((size_t)(k4 << 2) << 9);
        float4 w0 = *(const float4*)(wr);
        float4 w1 = *(const float4*)(wr + 512);
        float4 w2 = *(const float4*)(wr + 1024);
        float4 w3 = *(const float4*)(wr + 1536);
#pragma unroll
        for (int r = 0; r < 16; ++r) {
            float4 f = *(const float4*)&X_s[(rg << 4) + r][k4 << 2];
            FMA4(acc[r], f, w0, w1, w2, w3)
        }
    }

#pragma unroll
    for (int r = 0; r < 16; ++r)
        *(float4*)(io + ((size_t)(m0 + (rg << 4) + r)) * 512 + c4) = acc[r];
}

// ---------------------------------------------------------------------------
extern "C" void kernel_launch(void* const* d_in, const int* in_sizes, int n_in,
                              void* d_out, int out_size, void* d_ws, size_t ws_size,
                              hipStream_t stream) {
    const float* inputs = (const float*)d_in[0];   // [1024*49, 512]
    const float* qg     = (const float*)d_in[1];   // [64*49, 512]
    const float* qkv_w  = (const float*)d_in[2];   // [512, 1024]
    const float* qkv_b  = (const float*)d_in[3];   // [1024]
    const float* btab   = (const float*)d_in[4];   // [169, 16]
    const float* proj_w = (const float*)d_in[5];   // [512, 512]
    const float* proj_b = (const float*)d_in[6];   // [512]
    float* out = (float*)d_out;                    // [1024*49, 512]
    (void)d_ws; (void)ws_size;                     // zero-workspace design

    attn4<<<dim3(1024, 4), 256, 0, stream>>>(inputs, qg, qkv_w, qkv_b, btab, out);
    proj32<<<50176 / 32, 256, 0, stream>>>(proj_w, proj_b, out);
}